// Round 7
// baseline (803.117 us; speedup 1.0000x reference)
//
#include <hip/hip_runtime.h>
#include <hip/hip_bf16.h>

// Problem constants
#define B_    16
#define CI    512
#define CO    512
#define HH    64
#define WW    64
#define NPIX  4096          // 64*64
#define KTAPS 9
#define KTOT  (CI * KTAPS)  // 4608
#define LEAK  0.2f

// Padded channels-last image: [b][66][66][512] bf16 (1-px halo absorbs SAME pad)
// Holds style-premultiplied image: x[b,y,x,i] * style[b,i]
#define PY 66
#define PX 66
#define IMGPAD_ELEMS ((size_t)B_ * PY * PX * CI)

typedef __attribute__((ext_vector_type(8)))  __bf16 bf16x8;
typedef __attribute__((ext_vector_type(4)))  float  floatx4;
typedef __attribute__((ext_vector_type(16))) float  floatx16;

// Direct global->LDS 16B staging. LDS dest is wave-uniform base + lane*16;
// global addr is per-lane (lets us pre-swizzle the SOURCE, rule #21).
__device__ __forceinline__ void load_lds16(const __bf16* g, __bf16* l) {
    __builtin_amdgcn_global_load_lds(
        (const __attribute__((address_space(1))) unsigned int*)g,
        (__attribute__((address_space(3))) unsigned int*)(unsigned int)(uintptr_t)l,
        16, 0, 0);
}

// ---------------------------------------------------------------- prep kernels

// style[b][i] = sum_w w_embs[b][w] * style_w[i][w] + style_b[i] + 1
__global__ void style_kernel(const float* __restrict__ w_embs,
                             const float* __restrict__ style_w,
                             const float* __restrict__ style_b,
                             float* __restrict__ style) {
    int b = blockIdx.y;
    int i = blockIdx.x * 256 + threadIdx.x;
    const float4* we = (const float4*)(w_embs + (size_t)b * 512);
    const float4* sw = (const float4*)(style_w + (size_t)i * 512);
    float acc = 0.f;
    #pragma unroll 8
    for (int k = 0; k < 128; ++k) {
        float4 a = we[k], c = sw[k];
        acc += a.x * c.x + a.y * c.y + a.z * c.z + a.w * c.w;
    }
    style[b * 512 + i] = acc + style_b[i] + 1.0f;
}

// w2[o][i] = sum_tap conv_w[o][i][tap]^2
__global__ void w2_kernel(const float* __restrict__ conv_w, float* __restrict__ w2) {
    int idx = blockIdx.x * 256 + threadIdx.x;   // o*512+i, 262144 total
    const float* p = conv_w + (size_t)idx * 9;
    float s = 0.f;
    #pragma unroll
    for (int t = 0; t < 9; ++t) s += p[t] * p[t];
    w2[idx] = s;
}

// invn[b][o] = 1/sqrt( sum_i w2[o][i] * style[b][i]^2 )
// Wave-cooperative: lanes split the i-axis (coalesced w2 row reads, w2 read
// exactly once), 16 batch-partials per lane vs LDS style^2, butterfly reduce.
__global__ void invn_kernel(const float* __restrict__ w2,
                            const float* __restrict__ style,
                            float* __restrict__ invn) {
    __shared__ float st2[16 * 512];      // 32 KB: style^2, all batches
    int t = threadIdx.x;
    for (int idx = t * 4; idx < 16 * 512; idx += 256 * 4) {
        float4 s = *(const float4*)&style[idx];
        float4 q; q.x = s.x * s.x; q.y = s.y * s.y; q.z = s.z * s.z; q.w = s.w * s.w;
        *(float4*)&st2[idx] = q;
    }
    __syncthreads();
    int wv = t >> 6, lane = t & 63;
    int oBase = blockIdx.x * 32 + wv * 8;            // 16 blocks x 4 waves x 8 o
    #pragma unroll
    for (int oo = 0; oo < 8; ++oo) {
        int o = oBase + oo;
        const float4* wr = (const float4*)(w2 + (size_t)o * 512 + lane * 8);
        float4 a = wr[0], c = wr[1];
        float p[16];
        #pragma unroll
        for (int b = 0; b < 16; ++b) {
            const float4* s = (const float4*)&st2[b * 512 + lane * 8];
            float4 s0 = s[0], s1 = s[1];
            p[b] = a.x * s0.x + a.y * s0.y + a.z * s0.z + a.w * s0.w
                 + c.x * s1.x + c.y * s1.y + c.z * s1.z + c.w * s1.w;
        }
        #pragma unroll
        for (int d = 1; d < 64; d <<= 1)
            #pragma unroll
            for (int b = 0; b < 16; ++b) p[b] += __shfl_xor(p[b], d);
        if (lane < 16) invn[lane * 512 + o] = 1.0f / sqrtf(p[lane]);
    }
}

// Shared (batch-independent) bf16 weight, k-contiguous: wsh[o][tap*512 + i]
__global__ void wsh_kernel(const float* __restrict__ conv_w,
                           __bf16* __restrict__ wsh) {
    int o = blockIdx.x * 4 + (threadIdx.x >> 6);
    int i0 = (threadIdx.x & 63) * 8;
    const float* p = conv_w + ((size_t)o * 512 + i0) * 9;   // 72 contiguous floats
    float w[8][9];
    #pragma unroll
    for (int j = 0; j < 8; ++j)
        #pragma unroll
        for (int t = 0; t < 9; ++t) w[j][t] = p[j * 9 + t];
    __bf16* dstB = wsh + (size_t)o * KTOT + i0;
    #pragma unroll
    for (int t = 0; t < 9; ++t) {
        bf16x8 v;
        #pragma unroll
        for (int j = 0; j < 8; ++j) v[j] = (__bf16)w[j][t];
        *(bf16x8*)(dstB + t * 512) = v;
    }
}

// Zero only the halo ring of imgpad (260 px/batch instead of 71 MB memset)
__global__ void halo_kernel(__bf16* __restrict__ imgpad) {
    int t = blockIdx.x * 256 + threadIdx.x;
    if (t >= B_ * 260 * 64) return;
    int c8 = t & 63;
    int rest = t >> 6;
    int px = rest % 260;
    int b = rest / 260;
    int y, x;
    if (px < 66)       { y = 0;  x = px; }
    else if (px < 132) { y = 65; x = px - 66; }
    else { int s = px - 132; y = 1 + (s >> 1); x = (s & 1) * 65; }
    float4 z = {0.f, 0.f, 0.f, 0.f};
    *(float4*)&imgpad[(((size_t)b * PY + y) * PX + x) * 512 + c8 * 8] = z;
}

// NCHW fp32 -> padded channels-last bf16 [b][y][x][i], premultiplied by style.
// 64-channel x 2-row blocks: 128 B contiguous store segments; style regs and
// block setup amortized over 2 rows; 2x read ILP.
__global__ void imgpad_kernel(const float* __restrict__ imgs,
                              const float* __restrict__ style,
                              __bf16* __restrict__ imgpad) {
    __shared__ float tile[2][64][65];
    int ic = blockIdx.x, h0 = blockIdx.y * 2, b = blockIdx.z;
    int t = threadIdx.x;
    int i0 = ic * 64;
    {
        int li = t >> 2;            // 0..63 channel within chunk
        int w0 = (t & 3) * 16;      // 0,16,32,48
        #pragma unroll
        for (int r = 0; r < 2; ++r) {
            const float* src = imgs + (((size_t)(b * 512 + i0 + li) * 64 + h0 + r) * 64 + w0);
            float4 v0 = ((const float4*)src)[0];
            float4 v1 = ((const float4*)src)[1];
            float4 v2 = ((const float4*)src)[2];
            float4 v3 = ((const float4*)src)[3];
            tile[r][li][w0 +  0] = v0.x; tile[r][li][w0 +  1] = v0.y;
            tile[r][li][w0 +  2] = v0.z; tile[r][li][w0 +  3] = v0.w;
            tile[r][li][w0 +  4] = v1.x; tile[r][li][w0 +  5] = v1.y;
            tile[r][li][w0 +  6] = v1.z; tile[r][li][w0 +  7] = v1.w;
            tile[r][li][w0 +  8] = v2.x; tile[r][li][w0 +  9] = v2.y;
            tile[r][li][w0 + 10] = v2.z; tile[r][li][w0 + 11] = v2.w;
            tile[r][li][w0 + 12] = v3.x; tile[r][li][w0 + 13] = v3.y;
            tile[r][li][w0 + 14] = v3.z; tile[r][li][w0 + 15] = v3.w;
        }
    }
    __syncthreads();
    {
        int c0 = (t & 7) * 8;       // 0..56: 8 lanes x 16 B = 128 B segments
        float st[8];
        #pragma unroll
        for (int j = 0; j < 8; ++j) st[j] = style[b * 512 + i0 + c0 + j];
        #pragma unroll
        for (int r = 0; r < 2; ++r) {
            #pragma unroll
            for (int g = 0; g < 2; ++g) {
                int w = (t >> 3) + g * 32;   // 0..63
                bf16x8 v;
                #pragma unroll
                for (int j = 0; j < 8; ++j) v[j] = (__bf16)(tile[r][c0 + j][w] * st[j]);
                __bf16* dst = imgpad + (((size_t)b * PY + (h0 + r + 1)) * PX + (w + 1)) * 512 + i0 + c0;
                *(bf16x8*)dst = v;
            }
        }
    }
}

// ---------------------------------------------------------------- main conv
//
// 256x256 tile, BK=64, 8 waves (2M x 4N), 128 KiB LDS, 2 barriers per K-tile
// (R3 structure — best measured; R2/R4/R5 schedule variants all ~51% MfmaUtil).
// Round-6 change: MFMA shape 16x16x32 -> 32x32x16.
//  - ubench ceilings: 32x32 = 2495 TF vs 16x16 = 2075 TF (m06/m119): per-tile
//    matrix floor 2484 -> 2066 cyc.
//  - 32 MFMA/wave/tile instead of 64: each blocks its wave ~8 cyc -> the
//    other wave on the SIMD gets clean LDS-issue windows; issue pressure off.
//  - LDS traffic, staging, swizzle identical (24 b128 frag reads/wave/tile).
// Per-wave tile 128x64 = 4mi x 2ni frags of 32x32; acc = 4x2 floatx16 = 128 VGPR.
//
// Frag read addressing (row-major [256][64] bf16 tiles, 128 B rows, 8 chunks):
//   A-frag(mi,ks): lane l reads row wmi*128+mi*32+(l&31), global chunk
//   c = ks*2+(l>>5); staged LDS chunk = c ^ (row&7) = c ^ (l&7).
//   byte = rowbase + ((l>>5) ^ (l&7))*16, then ptr ^= (ks<<5)  [XOR safe:
//   only bits 5-6; LDS arrays aligned(128)].  B identical with wni*64+ni*32.
// C/D layout (m74/m101): col = lane&31, row = (reg&3)+8*(reg>>2)+4*(lane>>5).
//
// Hazard ledger (same as R3):
//  - Bs[p] bf reads: ALL issued before mid-BAR (consumed by ks0/ks1 MFMAs);
//    B(t+2) stages into Bs[p] after mid-BAR. OK.
//  - As[p^1] writes (A(t+1), tile front) vs t-1's af reads: retired before
//    t-1's last MFMA -> before t-1's end-BAR. OK.
//  - vmcnt(4) at tile end: outstanding <= B(t+1),A(t+1),B(t+2); waits until 4
//    remain = B(t+2) (consumed at t+2). Tail tiles drain to 0.

#define BM 256
#define BN 256
#define BK 64
#define NT 72   // K tiles: 9 taps * (512/64)

#define BAR() { __builtin_amdgcn_sched_barrier(0);                            \
                __builtin_amdgcn_s_barrier();                                 \
                __builtin_amdgcn_sched_barrier(0); }

// staging LDS dests (wave-uniform)
#define DSTA(BUFL, H, J) (&As[BUFL][(((H) * 128 + (J) * 64) + (wv << 3)) * 64])
#define DSTB(BUFL, H, J) (&Bs[BUFL][(((H) * 128 + (J) * 64) + (wv << 3)) * 64])

#define MFMA_KS(KS)                                                           \
    __builtin_amdgcn_s_setprio(1);                                            \
    _Pragma("unroll") for (int mi = 0; mi < 4; ++mi)                          \
      _Pragma("unroll") for (int ni = 0; ni < 2; ++ni)                        \
        acc[mi][ni] = __builtin_amdgcn_mfma_f32_32x32x16_bf16(                \
            af[mi], bfr[ni][KS], acc[mi][ni], 0, 0, 0);                       \
    __builtin_amdgcn_s_setprio(0);

#define RDA(BUF, MI, KS) (*(const bf16x8*)(pA[KS] + (BUF) * 32768 + (MI) * 4096))
#define RDB(BUF, NI, KS) (*(const bf16x8*)(pB[KS] + (BUF) * 32768 + (NI) * 4096))

#define TILE(BUF, T, DO_A, DO_B, VME) {                                       \
    if (DO_A) {                                                               \
        load_lds16(aG00, DSTA((BUF) ^ 1, 0, 0));                              \
        load_lds16(aG01, DSTA((BUF) ^ 1, 0, 1));                              \
        load_lds16(aG10, DSTA((BUF) ^ 1, 1, 0));                              \
        load_lds16(aG11, DSTA((BUF) ^ 1, 1, 1));                              \
        aG00 += 64; aG01 += 64; aG10 += 64; aG11 += 64;                       \
    }                                                                         \
    _Pragma("unroll") for (int ks = 0; ks < 4; ++ks)                          \
      _Pragma("unroll") for (int ni = 0; ni < 2; ++ni)                        \
        bfr[ni][ks] = RDB(BUF, ni, ks);                                       \
    _Pragma("unroll") for (int mi = 0; mi < 4; ++mi) af[mi] = RDA(BUF, mi, 0);\
    MFMA_KS(0)                                                                \
    _Pragma("unroll") for (int mi = 0; mi < 4; ++mi) af[mi] = RDA(BUF, mi, 1);\
    MFMA_KS(1)                                                                \
    BAR();   /* Bs[p] write guard: all bf reads are above */                  \
    if (DO_B) { int t2 = (T) + 2; int tap2 = t2 >> 3; int ic2 = t2 & 7;       \
        int dy2 = tap2 / 3, dx2 = tap2 - 3 * dy2;                             \
        int bd2 = (dy2 * PX + dx2) * 512 + ic2 * 64;                          \
        load_lds16(bG00 + bd2, DSTB(BUF, 0, 0));                              \
        load_lds16(bG01 + bd2, DSTB(BUF, 0, 1));                              \
        load_lds16(bG10 + bd2, DSTB(BUF, 1, 0));                              \
        load_lds16(bG11 + bd2, DSTB(BUF, 1, 1)); }                            \
    _Pragma("unroll") for (int mi = 0; mi < 4; ++mi) af[mi] = RDA(BUF, mi, 2);\
    MFMA_KS(2)                                                                \
    _Pragma("unroll") for (int mi = 0; mi < 4; ++mi) af[mi] = RDA(BUF, mi, 3);\
    MFMA_KS(3)                                                                \
    asm volatile("s_waitcnt vmcnt(" #VME ")" ::: "memory");                   \
    __builtin_amdgcn_sched_barrier(0);                                        \
    BAR();                                                                    \
}

// out[b,o,p] = leaky( invn[b,o] * (wsh[o,:] . ximg[b,p,:]) + conv_b[o] + noise*nw )
__global__ __launch_bounds__(512, 2) void conv_kernel(
    const __bf16* __restrict__ wsh,
    const __bf16* __restrict__ imgpad,
    const float*  __restrict__ invn,
    const float*  __restrict__ conv_b,
    const float*  __restrict__ noise,
    const float*  __restrict__ nw_p,
    float* __restrict__ out)
{
    __shared__ __attribute__((aligned(128))) __bf16 As[2][BM * BK];  // 64 KiB
    __shared__ __attribute__((aligned(128))) __bf16 Bs[2][BN * BK];  // 64 KiB

    const int tid = threadIdx.x;
    const int nt = blockIdx.x, mt = blockIdx.y, b = blockIdx.z;
    const int n0 = nt * BN, m0 = mt * BM;

    const int lane = tid & 63;
    const int wv = tid >> 6;          // 0..7
    const int wmi = wv & 1;           // M wave index (2)
    const int wni = wv >> 1;          // N wave index (4)

    const __bf16* iB = imgpad + (size_t)b * PY * PX * CI;

    // ---- staging per-thread constants (unchanged from R3)
    const int r0   = (wv << 3) + (lane >> 3);        // 0..63: row within 64-row quarter
    const int ks_g = (lane & 7) ^ (lane >> 3);       // pre-swizzled global k-slot

    // A sources (h,j): row = m0 + h*128 + j*64 + r0, k advances by running ptr
    const __bf16* aG00 = wsh + (size_t)(m0 +   0 +  0 + r0) * KTOT + ks_g * 8;
    const __bf16* aG01 = wsh + (size_t)(m0 +   0 + 64 + r0) * KTOT + ks_g * 8;
    const __bf16* aG10 = wsh + (size_t)(m0 + 128 +  0 + r0) * KTOT + ks_g * 8;
    const __bf16* aG11 = wsh + (size_t)(m0 + 128 + 64 + r0) * KTOT + ks_g * 8;

    // B sources (h,j): pixel p = n0 + h*128 + j*64 + r0 -> y = nt*4+2h+j, x = r0
    const __bf16* bG00 = iB + ((size_t)(nt * 4 + 0) * PX + r0) * 512 + ks_g * 8;
    const __bf16* bG01 = iB + ((size_t)(nt * 4 + 1) * PX + r0) * 512 + ks_g * 8;
    const __bf16* bG10 = iB + ((size_t)(nt * 4 + 2) * PX + r0) * 512 + ks_g * 8;
    const __bf16* bG11 = iB + ((size_t)(nt * 4 + 3) * PX + r0) * 512 + ks_g * 8;

    // ---- fragment-read per-lane bases (32x32 frags)
    const int l31 = lane & 31, lhi = lane >> 5, lm = lane & 7;
    const char* baseA = (const char*)&As[0][0] + wmi * 16384 + l31 * 128
                        + ((lhi ^ lm) << 4);
    const char* baseB = (const char*)&Bs[0][0] + wni * 8192  + l31 * 128
                        + ((lhi ^ lm) << 4);
    const char* pA[4];
    const char* pB[4];
    #pragma unroll
    for (int ks = 0; ks < 4; ++ks) {
        pA[ks] = (const char*)((uintptr_t)baseA ^ (uintptr_t)(ks << 5));
        pB[ks] = (const char*)((uintptr_t)baseB ^ (uintptr_t)(ks << 5));
    }

    floatx16 acc[4][2];
    #pragma unroll
    for (int mi = 0; mi < 4; ++mi)
        #pragma unroll
        for (int ni = 0; ni < 2; ++ni)
            acc[mi][ni] = (floatx16)(0.f);

    // ---- prologue: A(0)->As[0], B(0)->Bs[0], B(1)->Bs[1]; leave B(1) in flight
    load_lds16(aG00, DSTA(0, 0, 0));
    load_lds16(aG01, DSTA(0, 0, 1));
    load_lds16(aG10, DSTA(0, 1, 0));
    load_lds16(aG11, DSTA(0, 1, 1));
    aG00 += 64; aG01 += 64; aG10 += 64; aG11 += 64;   // now point at A(1)
    load_lds16(bG00, DSTB(0, 0, 0));          // bd(0) = 0 (tap0, ic0)
    load_lds16(bG01, DSTB(0, 0, 1));
    load_lds16(bG10, DSTB(0, 1, 0));
    load_lds16(bG11, DSTB(0, 1, 1));
    load_lds16(bG00 + 64, DSTB(1, 0, 0));     // bd(1) = 64 (tap0, ic1)
    load_lds16(bG01 + 64, DSTB(1, 0, 1));
    load_lds16(bG10 + 64, DSTB(1, 1, 0));
    load_lds16(bG11 + 64, DSTB(1, 1, 1));
    asm volatile("s_waitcnt vmcnt(4)" ::: "memory");
    __builtin_amdgcn_sched_barrier(0);
    BAR();

    bf16x8 af[4];
    bf16x8 bfr[2][4];

    #pragma unroll 1
    for (int it = 0; it < 35; ++it) {
        int t0 = it * 2;
        TILE(0, t0,     true, true, 4)
        TILE(1, t0 + 1, true, true, 4)
    }
    // tiles 70, 71: no B prefetch left; tile 70 stages A(71) then drains fully
    TILE(0, 70, true,  false, 0)
    TILE(1, 71, false, false, 0)

    // ---- epilogue: * invn[b,o] + conv_b + noise*nw, LeakyReLU(0.2)
    // C/D: col = lane&31, row = (rr&3) + 8*(rr>>2) + 4*(lane>>5)
    float nwv = nw_p[0];
    #pragma unroll
    for (int ni = 0; ni < 2; ++ni) {
        int col = n0 + wni * 64 + ni * 32 + l31;         // pixel
        float nz = noise[b * NPIX + col] * nwv;
        #pragma unroll
        for (int mi = 0; mi < 4; ++mi) {
            int rowb = m0 + wmi * 128 + mi * 32 + 4 * lhi;
            #pragma unroll
            for (int rr = 0; rr < 16; ++rr) {
                int row = rowb + (rr & 3) + 8 * (rr >> 2);
                float sc = invn[b * 512 + row];
                float vv = acc[mi][ni][rr] * sc + conv_b[row] + nz;
                out[(((size_t)b * CO + row) << 12) + col] = vv >= 0.f ? vv : LEAK * vv;
            }
        }
    }
}

// ---------------------------------------------------------------- launch

extern "C" void kernel_launch(void* const* d_in, const int* in_sizes, int n_in,
                              void* d_out, int out_size, void* d_ws, size_t ws_size,
                              hipStream_t stream) {
    const float* imgs    = (const float*)d_in[0];
    const float* w_embs  = (const float*)d_in[1];
    const float* noise   = (const float*)d_in[2];
    const float* conv_w  = (const float*)d_in[3];
    const float* conv_b  = (const float*)d_in[4];
    const float* style_w = (const float*)d_in[5];
    const float* style_b = (const float*)d_in[6];
    const float* nw      = (const float*)d_in[7];
    float* out = (float*)d_out;

    char* ws = (char*)d_ws;
    size_t off = 0;
    __bf16* wsh = (__bf16*)(ws + off);       off += (size_t)CO * KTOT * 2;           // 4.7 MB
    __bf16* imgpad = (__bf16*)(ws + off);    off += IMGPAD_ELEMS * 2;                // 71.4 MB
    float* style = (float*)(ws + off);       off += (size_t)B_ * CI * 4;
    float* invn  = (float*)(ws + off);       off += (size_t)B_ * CO * 4;
    float* w2    = (float*)(ws + off);       off += (size_t)CO * CI * 4;

    style_kernel<<<dim3(2, B_), 256, 0, stream>>>(w_embs, style_w, style_b, style);
    w2_kernel<<<dim3(1024), 256, 0, stream>>>(conv_w, w2);
    invn_kernel<<<dim3(16), 256, 0, stream>>>(w2, style, invn);
    wsh_kernel<<<dim3(CO / 4), 256, 0, stream>>>(conv_w, wsh);
    halo_kernel<<<dim3((B_ * 260 * 64 + 255) / 256), 256, 0, stream>>>(imgpad);
    imgpad_kernel<<<dim3(8, 32, B_), 256, 0, stream>>>(imgs, style, imgpad);
    conv_kernel<<<dim3(NPIX / BN, CO / BM, B_), 512, 0, stream>>>(
        wsh, imgpad, invn, conv_b, noise, nw, out);
}

// Round 8
// 524.104 us; speedup vs baseline: 1.5324x; 1.5324x over previous
//
#include <hip/hip_runtime.h>
#include <hip/hip_bf16.h>

// Problem constants
#define B_    16
#define CI    512
#define CO    512
#define HH    64
#define WW    64
#define NPIX  4096          // 64*64
#define KTAPS 9
#define KTOT  (CI * KTAPS)  // 4608
#define LEAK  0.2f

// Padded channels-last image: [b][66][66][512] bf16 (1-px halo absorbs SAME pad)
// Holds style-premultiplied image: x[b,y,x,i] * style[b,i]
#define PY 66
#define PX 66
#define IMGPAD_ELEMS ((size_t)B_ * PY * PX * CI)

typedef __attribute__((ext_vector_type(8))) __bf16  bf16x8;
typedef __attribute__((ext_vector_type(4))) float   floatx4;

// Direct global->LDS 16B staging. LDS dest is wave-uniform base + lane*16;
// global addr is per-lane (lets us pre-swizzle the SOURCE, rule #21).
__device__ __forceinline__ void load_lds16(const __bf16* g, __bf16* l) {
    __builtin_amdgcn_global_load_lds(
        (const __attribute__((address_space(1))) unsigned int*)g,
        (__attribute__((address_space(3))) unsigned int*)(unsigned int)(uintptr_t)l,
        16, 0, 0);
}

// ---------------------------------------------------------------- prep kernels

// style[b][i] = sum_w w_embs[b][w] * style_w[i][w] + style_b[i] + 1
__global__ void style_kernel(const float* __restrict__ w_embs,
                             const float* __restrict__ style_w,
                             const float* __restrict__ style_b,
                             float* __restrict__ style) {
    int b = blockIdx.y;
    int i = blockIdx.x * 256 + threadIdx.x;
    const float4* we = (const float4*)(w_embs + (size_t)b * 512);
    const float4* sw = (const float4*)(style_w + (size_t)i * 512);
    float acc = 0.f;
    #pragma unroll 8
    for (int k = 0; k < 128; ++k) {
        float4 a = we[k], c = sw[k];
        acc += a.x * c.x + a.y * c.y + a.z * c.z + a.w * c.w;
    }
    style[b * 512 + i] = acc + style_b[i] + 1.0f;
}

// Fused: wsh (bf16 k-contiguous weight) + w2 (per-(o,i) tap-sum of squares,
// computed from the already-loaded registers — one conv_w pass instead of two)
// + halo zeroing (extra blocks; independent work, no barrier in kernel).
__global__ void wshw2halo_kernel(const float* __restrict__ conv_w,
                                 __bf16* __restrict__ wsh,
                                 float* __restrict__ w2,
                                 __bf16* __restrict__ imgpad) {
    int blk = blockIdx.x;
    if (blk >= CO / 4) {
        // halo: zero the 1-px ring (260 px/batch, 512 ch, 16 B granules)
        int base = (blk - CO / 4) * 256 + threadIdx.x;
        for (int t = base; t < B_ * 260 * 64; t += 32 * 256) {
            int c8 = t & 63;
            int rest = t >> 6;
            int px = rest % 260;
            int b = rest / 260;
            int y, x;
            if (px < 66)       { y = 0;  x = px; }
            else if (px < 132) { y = 65; x = px - 66; }
            else { int s = px - 132; y = 1 + (s >> 1); x = (s & 1) * 65; }
            float4 z = {0.f, 0.f, 0.f, 0.f};
            *(float4*)&imgpad[(((size_t)b * PY + y) * PX + x) * 512 + c8 * 8] = z;
        }
        return;
    }
    int o = blk * 4 + (threadIdx.x >> 6);
    int i0 = (threadIdx.x & 63) * 8;
    const float* p = conv_w + ((size_t)o * 512 + i0) * 9;   // 72 contiguous floats
    float w[8][9];
    #pragma unroll
    for (int j = 0; j < 8; ++j)
        #pragma unroll
        for (int t = 0; t < 9; ++t) w[j][t] = p[j * 9 + t];
    __bf16* dstB = wsh + (size_t)o * KTOT + i0;
    #pragma unroll
    for (int t = 0; t < 9; ++t) {
        bf16x8 v;
        #pragma unroll
        for (int j = 0; j < 8; ++j) v[j] = (__bf16)w[j][t];
        *(bf16x8*)(dstB + t * 512) = v;
    }
    float s[8];
    #pragma unroll
    for (int j = 0; j < 8; ++j) {
        float a = 0.f;
        #pragma unroll
        for (int t = 0; t < 9; ++t) a += w[j][t] * w[j][t];
        s[j] = a;
    }
    float4* w2p = (float4*)(w2 + (size_t)o * 512 + i0);
    w2p[0] = make_float4(s[0], s[1], s[2], s[3]);
    w2p[1] = make_float4(s[4], s[5], s[6], s[7]);
}

// invn[b][o] = 1/sqrt( sum_i w2[o][i] * style[b][i]^2 )
// Wave-cooperative: lanes split the i-axis (coalesced w2 row reads, w2 read
// exactly once), 16 batch-partials per lane vs LDS style^2, butterfly reduce.
__global__ void invn_kernel(const float* __restrict__ w2,
                            const float* __restrict__ style,
                            float* __restrict__ invn) {
    __shared__ float st2[16 * 512];      // 32 KB: style^2, all batches
    int t = threadIdx.x;
    for (int idx = t * 4; idx < 16 * 512; idx += 256 * 4) {
        float4 s = *(const float4*)&style[idx];
        float4 q; q.x = s.x * s.x; q.y = s.y * s.y; q.z = s.z * s.z; q.w = s.w * s.w;
        *(float4*)&st2[idx] = q;
    }
    __syncthreads();
    int wv = t >> 6, lane = t & 63;
    int oBase = blockIdx.x * 32 + wv * 8;            // 16 blocks x 4 waves x 8 o
    #pragma unroll
    for (int oo = 0; oo < 8; ++oo) {
        int o = oBase + oo;
        const float4* wr = (const float4*)(w2 + (size_t)o * 512 + lane * 8);
        float4 a = wr[0], c = wr[1];
        float p[16];
        #pragma unroll
        for (int b = 0; b < 16; ++b) {
            const float4* s = (const float4*)&st2[b * 512 + lane * 8];
            float4 s0 = s[0], s1 = s[1];
            p[b] = a.x * s0.x + a.y * s0.y + a.z * s0.z + a.w * s0.w
                 + c.x * s1.x + c.y * s1.y + c.z * s1.z + c.w * s1.w;
        }
        #pragma unroll
        for (int d = 1; d < 64; d <<= 1)
            #pragma unroll
            for (int b = 0; b < 16; ++b) p[b] += __shfl_xor(p[b], d);
        if (lane < 16) invn[lane * 512 + o] = 1.0f / sqrtf(p[lane]);
    }
}

// NCHW fp32 -> padded channels-last bf16 [b][y][x][i], premultiplied by style.
// 64-channel x 2-row blocks: 128 B contiguous store segments; style regs and
// block setup amortized over 2 rows; 2x read ILP.
__global__ void imgpad_kernel(const float* __restrict__ imgs,
                              const float* __restrict__ style,
                              __bf16* __restrict__ imgpad) {
    __shared__ float tile[2][64][65];
    int ic = blockIdx.x, h0 = blockIdx.y * 2, b = blockIdx.z;
    int t = threadIdx.x;
    int i0 = ic * 64;
    {
        int li = t >> 2;            // 0..63 channel within chunk
        int w0 = (t & 3) * 16;      // 0,16,32,48
        #pragma unroll
        for (int r = 0; r < 2; ++r) {
            const float* src = imgs + (((size_t)(b * 512 + i0 + li) * 64 + h0 + r) * 64 + w0);
            float4 v0 = ((const float4*)src)[0];
            float4 v1 = ((const float4*)src)[1];
            float4 v2 = ((const float4*)src)[2];
            float4 v3 = ((const float4*)src)[3];
            tile[r][li][w0 +  0] = v0.x; tile[r][li][w0 +  1] = v0.y;
            tile[r][li][w0 +  2] = v0.z; tile[r][li][w0 +  3] = v0.w;
            tile[r][li][w0 +  4] = v1.x; tile[r][li][w0 +  5] = v1.y;
            tile[r][li][w0 +  6] = v1.z; tile[r][li][w0 +  7] = v1.w;
            tile[r][li][w0 +  8] = v2.x; tile[r][li][w0 +  9] = v2.y;
            tile[r][li][w0 + 10] = v2.z; tile[r][li][w0 + 11] = v2.w;
            tile[r][li][w0 + 12] = v3.x; tile[r][li][w0 + 13] = v3.y;
            tile[r][li][w0 + 14] = v3.z; tile[r][li][w0 + 15] = v3.w;
        }
    }
    __syncthreads();
    {
        int c0 = (t & 7) * 8;       // 0..56: 8 lanes x 16 B = 128 B segments
        float st[8];
        #pragma unroll
        for (int j = 0; j < 8; ++j) st[j] = style[b * 512 + i0 + c0 + j];
        #pragma unroll
        for (int r = 0; r < 2; ++r) {
            #pragma unroll
            for (int g = 0; g < 2; ++g) {
                int w = (t >> 3) + g * 32;   // 0..63
                bf16x8 v;
                #pragma unroll
                for (int j = 0; j < 8; ++j) v[j] = (__bf16)(tile[r][c0 + j][w] * st[j]);
                __bf16* dst = imgpad + (((size_t)b * PY + (h0 + r + 1)) * PX + (w + 1)) * 512 + i0 + c0;
                *(bf16x8*)dst = v;
            }
        }
    }
}

// ---------------------------------------------------------------- main conv
//
// EXACT Round-3 structure (best measured: conv 269 us, MfmaUtil 53.3,
// SQ_LDS_BANK_CONFLICT == 0). R4 (A-hoist), R5 (1-barrier/triple-buf) and
// R7 (32x32x16 shape) all regressed — the 16x16x32 + this read pattern is
// the empirically-proven combination; do not "improve" it without A/B data.
//
// 256x256 tile, BK=64, 8 waves (2M x 4N), 128 KiB LDS, 2 barriers per K-tile:
//   ph0: read 8 bf + 4 af ; stage A-half0(t+1) ; M0
//   ph1: read 4 af        ; stage A-half1(t+1) ; M1
//   BAR          <- Bs[p] write guard
//   ph2: read 4 af        ; stage B-half0(t+2) ; M2
//   ph3: read 4 af        ; stage B-half1(t+2) ; M3
//   vmcnt(4) ; BAR
//
// Hazard ledger:
//  - Bs[p] writes (B(t+2), ph2/3) vs Bs[p] reads (bf, ph0): every wave's bf
//    reads retire before its M0/M1; all waves past M1 at mid-BAR; stages
//    issue after it. OK.
//  - As[p^1] writes (A(t+1), ph0/1) vs t-1's af reads: retired before t-1's
//    M3 -> before t-1's end-BAR. OK.
//  - vmcnt(4) at tile end: outstanding = B(t+1),A(t+1),B(t+2) (issue order);
//    drains B(t+1)+A(t+1), leaves B(t+2) in flight. Tails drain to 0.
// LDS swizzle: linear LDS dest; global SOURCE k-slot permuted per lane
// (slot = (l&7)^(l>>3)); frag reads use slot = kslot ^ (row&7).

#define BM 256
#define BN 256
#define BK 64
#define NT 72   // K tiles: 9 taps * (512/64)

#define BAR() { __builtin_amdgcn_sched_barrier(0);                            \
                __builtin_amdgcn_s_barrier();                                 \
                __builtin_amdgcn_sched_barrier(0); }

// frag reads: PTR carries lane base (+wave row block, +r16*128, +slot for its ks)
#define RA(PTR, BUFL, MI) (*(const bf16x8*)((PTR) + (BUFL) * 32768 + (MI) * 2048))
#define RB(PTR, BUFL, NI) (*(const bf16x8*)((PTR) + (BUFL) * 32768 + (NI) * 2048))

// staging LDS dests (wave-uniform)
#define DSTA(BUFL, H, J) (&As[BUFL][(((H) * 128 + (J) * 64) + (wv << 3)) * 64])
#define DSTB(BUFL, H, J) (&Bs[BUFL][(((H) * 128 + (J) * 64) + (wv << 3)) * 64])

#define MFMA_PH(Q)                                                            \
    __builtin_amdgcn_s_setprio(1);                                            \
    _Pragma("unroll") for (int e = 0; e < 2; ++e) {                           \
      _Pragma("unroll") for (int ni = 0; ni < 4; ++ni) {                      \
        acc[2*(Q)+e][ni] = __builtin_amdgcn_mfma_f32_16x16x32_bf16(           \
            af[e][0], bf[ni][0], acc[2*(Q)+e][ni], 0, 0, 0);                  \
        acc[2*(Q)+e][ni] = __builtin_amdgcn_mfma_f32_16x16x32_bf16(           \
            af[e][1], bf[ni][1], acc[2*(Q)+e][ni], 0, 0, 0);                  \
      }                                                                       \
    }                                                                         \
    __builtin_amdgcn_s_setprio(0);

#define TILE(BUF, T, DO_A, DO_B, VME) {                                       \
    /* ph0: all B-frags + A mi0,1; stage A-half0(T+1) */                      \
    _Pragma("unroll") for (int ni = 0; ni < 4; ++ni) {                        \
        bf[ni][0] = RB(ldsB0, BUF, ni); bf[ni][1] = RB(ldsB1, BUF, ni);       \
    }                                                                         \
    af[0][0] = RA(ldsA0, BUF, 0); af[0][1] = RA(ldsA1, BUF, 0);               \
    af[1][0] = RA(ldsA0, BUF, 1); af[1][1] = RA(ldsA1, BUF, 1);               \
    if (DO_A) { int ka = ((T) + 1) * 64;                                      \
        load_lds16(aG00 + ka, DSTA((BUF) ^ 1, 0, 0));                         \
        load_lds16(aG01 + ka, DSTA((BUF) ^ 1, 0, 1)); }                       \
    MFMA_PH(0)                                                                \
    /* ph1: A mi2,3; stage A-half1(T+1) */                                    \
    af[0][0] = RA(ldsA0, BUF, 2); af[0][1] = RA(ldsA1, BUF, 2);               \
    af[1][0] = RA(ldsA0, BUF, 3); af[1][1] = RA(ldsA1, BUF, 3);               \
    if (DO_A) { int ka = ((T) + 1) * 64;                                      \
        load_lds16(aG10 + ka, DSTA((BUF) ^ 1, 1, 0));                         \
        load_lds16(aG11 + ka, DSTA((BUF) ^ 1, 1, 1)); }                       \
    MFMA_PH(1)                                                                \
    BAR();   /* B-region guard */                                             \
    /* ph2: A mi4,5; stage B-half0(T+2) */                                    \
    af[0][0] = RA(ldsA0, BUF, 4); af[0][1] = RA(ldsA1, BUF, 4);               \
    af[1][0] = RA(ldsA0, BUF, 5); af[1][1] = RA(ldsA1, BUF, 5);               \
    int bd2_##BUF = 0; (void)bd2_##BUF;                                       \
    if (DO_B) { int t2 = (T) + 2; int tap2 = t2 >> 3; int ic2 = t2 & 7;       \
        int dy2 = tap2 / 3, dx2 = tap2 - 3 * dy2;                             \
        bd2_##BUF = (dy2 * PX + dx2) * 512 + ic2 * 64;                        \
        load_lds16(bG00 + bd2_##BUF, DSTB(BUF, 0, 0));                        \
        load_lds16(bG01 + bd2_##BUF, DSTB(BUF, 0, 1)); }                      \
    MFMA_PH(2)                                                                \
    /* ph3: A mi6,7; stage B-half1(T+2); counted vmcnt */                     \
    af[0][0] = RA(ldsA0, BUF, 6); af[0][1] = RA(ldsA1, BUF, 6);               \
    af[1][0] = RA(ldsA0, BUF, 7); af[1][1] = RA(ldsA1, BUF, 7);               \
    if (DO_B) {                                                               \
        load_lds16(bG10 + bd2_##BUF, DSTB(BUF, 1, 0));                        \
        load_lds16(bG11 + bd2_##BUF, DSTB(BUF, 1, 1)); }                      \
    MFMA_PH(3)                                                                \
    asm volatile("s_waitcnt vmcnt(" #VME ")" ::: "memory");                   \
    __builtin_amdgcn_sched_barrier(0);                                        \
    BAR();                                                                    \
}

// out[b,o,p] = leaky( invn[b,o] * (wsh[o,:] . ximg[b,p,:]) + conv_b[o] + noise*nw )
__global__ __launch_bounds__(512, 2) void conv_kernel(
    const __bf16* __restrict__ wsh,
    const __bf16* __restrict__ imgpad,
    const float*  __restrict__ invn,
    const float*  __restrict__ conv_b,
    const float*  __restrict__ noise,
    const float*  __restrict__ nw_p,
    float* __restrict__ out)
{
    __shared__ __attribute__((aligned(16))) __bf16 As[2][BM * BK];  // 64 KiB
    __shared__ __attribute__((aligned(16))) __bf16 Bs[2][BN * BK];  // 64 KiB

    const int tid = threadIdx.x;
    const int nt = blockIdx.x, mt = blockIdx.y, b = blockIdx.z;
    const int n0 = nt * BN, m0 = mt * BM;

    const int lane = tid & 63;
    const int wv = tid >> 6;          // 0..7
    const int wmi = wv & 1;           // M wave index (2)
    const int wni = wv >> 1;          // N wave index (4)

    const __bf16* iB = imgpad + (size_t)b * PY * PX * CI;

    // ---- staging per-thread constants
    const int r0   = (wv << 3) + (lane >> 3);        // 0..63: row within 64-row quarter
    const int ks_g = (lane & 7) ^ (lane >> 3);       // pre-swizzled global k-slot

    // A sources (h,j): row = m0 + h*128 + j*64 + r0, k = tile*64 + ks_g*8
    const __bf16* aG00 = wsh + (size_t)(m0 +   0 +  0 + r0) * KTOT + ks_g * 8;
    const __bf16* aG01 = wsh + (size_t)(m0 +   0 + 64 + r0) * KTOT + ks_g * 8;
    const __bf16* aG10 = wsh + (size_t)(m0 + 128 +  0 + r0) * KTOT + ks_g * 8;
    const __bf16* aG11 = wsh + (size_t)(m0 + 128 + 64 + r0) * KTOT + ks_g * 8;

    // B sources (h,j): pixel p = n0 + h*128 + j*64 + r0 -> y = nt*4+2h+j, x = r0
    const __bf16* bG00 = iB + ((size_t)(nt * 4 + 0) * PX + r0) * 512 + ks_g * 8;
    const __bf16* bG01 = iB + ((size_t)(nt * 4 + 1) * PX + r0) * 512 + ks_g * 8;
    const __bf16* bG10 = iB + ((size_t)(nt * 4 + 2) * PX + r0) * 512 + ks_g * 8;
    const __bf16* bG11 = iB + ((size_t)(nt * 4 + 3) * PX + r0) * 512 + ks_g * 8;

    // ---- fragment-read per-lane bases (byte math; slot = kslot ^ (row&7))
    const int r16 = lane & 15, q4 = lane >> 4, r7 = lane & 7;
    const int s0 = (q4 ^ r7) << 4;                   // ks=0 slot bytes
    const char* ldsA0 = (const char*)&As[0][0] + wmi * 16384 + r16 * 128 + s0;
    const char* ldsA1 = (const char*)&As[0][0] + wmi * 16384 + r16 * 128 + (s0 ^ 64);
    const char* ldsB0 = (const char*)&Bs[0][0] + wni * 8192  + r16 * 128 + s0;
    const char* ldsB1 = (const char*)&Bs[0][0] + wni * 8192  + r16 * 128 + (s0 ^ 64);

    floatx4 acc[8][4];
    #pragma unroll
    for (int mi = 0; mi < 8; ++mi)
        #pragma unroll
        for (int ni = 0; ni < 4; ++ni)
            acc[mi][ni] = (floatx4)(0.f);

    // ---- prologue: A(0), B(0), B(1); leave B(1) in flight
    load_lds16(aG00, DSTA(0, 0, 0));
    load_lds16(aG01, DSTA(0, 0, 1));
    load_lds16(aG10, DSTA(0, 1, 0));
    load_lds16(aG11, DSTA(0, 1, 1));
    load_lds16(bG00, DSTB(0, 0, 0));          // bd(0) = 0 (tap0, ic0)
    load_lds16(bG01, DSTB(0, 0, 1));
    load_lds16(bG10, DSTB(0, 1, 0));
    load_lds16(bG11, DSTB(0, 1, 1));
    load_lds16(bG00 + 64, DSTB(1, 0, 0));     // bd(1) = 64 (tap0, ic1)
    load_lds16(bG01 + 64, DSTB(1, 0, 1));
    load_lds16(bG10 + 64, DSTB(1, 1, 0));
    load_lds16(bG11 + 64, DSTB(1, 1, 1));
    asm volatile("s_waitcnt vmcnt(4)" ::: "memory");
    __builtin_amdgcn_sched_barrier(0);
    BAR();

    bf16x8 af[2][2];
    bf16x8 bf[4][2];

    #pragma unroll 1
    for (int it = 0; it < 35; ++it) {
        int t0 = it * 2;
        TILE(0, t0,     true, true, 4)
        TILE(1, t0 + 1, true, true, 4)
    }
    // tiles 70, 71: no B prefetch left; tile 70 stages A(71) then drains fully
    TILE(0, 70, true,  false, 0)
    TILE(1, 71, false, false, 0)

    // ---- epilogue: * invn[b,o] + conv_b + noise*nw, LeakyReLU(0.2)
    float nwv = nw_p[0];
    #pragma unroll
    for (int ni = 0; ni < 4; ++ni) {
        int col = n0 + wni * 64 + ni * 16 + r16;         // pixel
        float nz = noise[b * NPIX + col] * nwv;
        #pragma unroll
        for (int mi = 0; mi < 8; ++mi) {
            int rowo = m0 + wmi * 128 + mi * 16 + q4 * 4; // output channel base
            #pragma unroll
            for (int rr = 0; rr < 4; ++rr) {
                float sc = invn[b * 512 + rowo + rr];
                float vv = acc[mi][ni][rr] * sc + conv_b[rowo + rr] + nz;
                out[(((size_t)b * CO + rowo + rr) << 12) + col] = vv >= 0.f ? vv : LEAK * vv;
            }
        }
    }
}

// ---------------------------------------------------------------- launch

extern "C" void kernel_launch(void* const* d_in, const int* in_sizes, int n_in,
                              void* d_out, int out_size, void* d_ws, size_t ws_size,
                              hipStream_t stream) {
    const float* imgs    = (const float*)d_in[0];
    const float* w_embs  = (const float*)d_in[1];
    const float* noise   = (const float*)d_in[2];
    const float* conv_w  = (const float*)d_in[3];
    const float* conv_b  = (const float*)d_in[4];
    const float* style_w = (const float*)d_in[5];
    const float* style_b = (const float*)d_in[6];
    const float* nw      = (const float*)d_in[7];
    float* out = (float*)d_out;

    char* ws = (char*)d_ws;
    size_t off = 0;
    __bf16* wsh = (__bf16*)(ws + off);       off += (size_t)CO * KTOT * 2;           // 4.7 MB
    __bf16* imgpad = (__bf16*)(ws + off);    off += IMGPAD_ELEMS * 2;                // 71.4 MB
    float* style = (float*)(ws + off);       off += (size_t)B_ * CI * 4;
    float* invn  = (float*)(ws + off);       off += (size_t)B_ * CO * 4;
    float* w2    = (float*)(ws + off);       off += (size_t)CO * CI * 4;

    style_kernel<<<dim3(2, B_), 256, 0, stream>>>(w_embs, style_w, style_b, style);
    wshw2halo_kernel<<<dim3(CO / 4 + 32), 256, 0, stream>>>(conv_w, wsh, w2, imgpad);
    invn_kernel<<<dim3(16), 256, 0, stream>>>(w2, style, invn);
    imgpad_kernel<<<dim3(8, 32, B_), 256, 0, stream>>>(imgs, style, imgpad);
    conv_kernel<<<dim3(NPIX / BN, CO / BM, B_), 512, 0, stream>>>(
        wsh, imgpad, invn, conv_b, noise, nw, out);
}

// Round 9
// 495.610 us; speedup vs baseline: 1.6205x; 1.0575x over previous
//
#include <hip/hip_runtime.h>
#include <hip/hip_bf16.h>

// Problem constants
#define B_    16
#define CI    512
#define CO    512
#define HH    64
#define WW    64
#define NPIX  4096          // 64*64
#define KTAPS 9
#define KTOT  (CI * KTAPS)  // 4608
#define LEAK  0.2f

// Padded channels-last image: [b][66][66][512] bf16 (1-px halo absorbs SAME pad)
// Holds style-premultiplied image: x[b,y,x,i] * style[b,i]
#define PY 66
#define PX 66
#define IMGPAD_ELEMS ((size_t)B_ * PY * PX * CI)

typedef __attribute__((ext_vector_type(8))) __bf16  bf16x8;
typedef __attribute__((ext_vector_type(4))) float   floatx4;

// Direct global->LDS 16B staging. LDS dest is wave-uniform base + lane*16;
// global addr is per-lane (lets us pre-swizzle the SOURCE, rule #21).
__device__ __forceinline__ void load_lds16(const __bf16* g, __bf16* l) {
    __builtin_amdgcn_global_load_lds(
        (const __attribute__((address_space(1))) unsigned int*)g,
        (__attribute__((address_space(3))) unsigned int*)(unsigned int)(uintptr_t)l,
        16, 0, 0);
}

// ---------------------------------------------------------------- prep phase 1
// All mutually independent: style | wsh+w2 | halo.  Block ranges:
//   0..31    style   (b = blk>>1, i-half = blk&1)
//   32..159  wsh+w2  (128 blocks, 4 o each)
//   160..191 halo    (grid-stride over ring granules)
__global__ void prep1_kernel(const float* __restrict__ w_embs,
                             const float* __restrict__ style_w,
                             const float* __restrict__ style_b,
                             const float* __restrict__ conv_w,
                             float* __restrict__ style,
                             __bf16* __restrict__ wsh,
                             float* __restrict__ w2,
                             __bf16* __restrict__ imgpad) {
    int blk = blockIdx.x;
    if (blk < 32) {
        // ---- style[b][i] = w_embs[b]·style_w[i] + style_b[i] + 1
        int b = blk >> 1;
        int i = (blk & 1) * 256 + threadIdx.x;
        const float4* we = (const float4*)(w_embs + (size_t)b * 512);
        const float4* sw = (const float4*)(style_w + (size_t)i * 512);
        float acc = 0.f;
        #pragma unroll 8
        for (int k = 0; k < 128; ++k) {
            float4 a = we[k], c = sw[k];
            acc += a.x * c.x + a.y * c.y + a.z * c.z + a.w * c.w;
        }
        style[b * 512 + i] = acc + style_b[i] + 1.0f;
    } else if (blk < 160) {
        // ---- wsh (bf16 k-contiguous weight) + w2 (tap sum-of-squares), one
        // conv_w pass for both.
        int o = (blk - 32) * 4 + (threadIdx.x >> 6);
        int i0 = (threadIdx.x & 63) * 8;
        const float* p = conv_w + ((size_t)o * 512 + i0) * 9;   // 72 contiguous
        float w[8][9];
        #pragma unroll
        for (int j = 0; j < 8; ++j)
            #pragma unroll
            for (int t = 0; t < 9; ++t) w[j][t] = p[j * 9 + t];
        __bf16* dstB = wsh + (size_t)o * KTOT + i0;
        #pragma unroll
        for (int t = 0; t < 9; ++t) {
            bf16x8 v;
            #pragma unroll
            for (int j = 0; j < 8; ++j) v[j] = (__bf16)w[j][t];
            *(bf16x8*)(dstB + t * 512) = v;
        }
        float s[8];
        #pragma unroll
        for (int j = 0; j < 8; ++j) {
            float a = 0.f;
            #pragma unroll
            for (int t = 0; t < 9; ++t) a += w[j][t] * w[j][t];
            s[j] = a;
        }
        float4* w2p = (float4*)(w2 + (size_t)o * 512 + i0);
        w2p[0] = make_float4(s[0], s[1], s[2], s[3]);
        w2p[1] = make_float4(s[4], s[5], s[6], s[7]);
    } else {
        // ---- halo: zero the 1-px ring (260 px/batch, 512 ch, 16 B granules)
        int base = (blk - 160) * 256 + threadIdx.x;
        for (int t = base; t < B_ * 260 * 64; t += 32 * 256) {
            int c8 = t & 63;
            int rest = t >> 6;
            int px = rest % 260;
            int b = rest / 260;
            int y, x;
            if (px < 66)       { y = 0;  x = px; }
            else if (px < 132) { y = 65; x = px - 66; }
            else { int s = px - 132; y = 1 + (s >> 1); x = (s & 1) * 65; }
            float4 z = {0.f, 0.f, 0.f, 0.f};
            *(float4*)&imgpad[(((size_t)b * PY + y) * PX + x) * 512 + c8 * 8] = z;
        }
    }
}

// ---------------------------------------------------------------- prep phase 2
// Both depend only on prep1: invn | imgpad.  Block ranges:
//   0..15      invn   (wave-cooperative, R4-proven body)
//   16..4111   imgpad (ic = idx&7, h0 = ((idx>>3)&31)*2, b = idx>>8)
__global__ void prep2_kernel(const float* __restrict__ w2,
                             const float* __restrict__ style,
                             const float* __restrict__ imgs,
                             float* __restrict__ invn,
                             __bf16* __restrict__ imgpad) {
    int blk = blockIdx.x;
    if (blk < 16) {
        // ---- invn[b][o] = 1/sqrt( sum_i w2[o][i]*style[b][i]^2 ); lanes split
        // the i-axis (coalesced w2 rows, read once), butterfly reduce.
        __shared__ float st2[16 * 512];      // 32 KB: style^2, all batches
        int t = threadIdx.x;
        for (int idx = t * 4; idx < 16 * 512; idx += 256 * 4) {
            float4 s = *(const float4*)&style[idx];
            float4 q; q.x = s.x * s.x; q.y = s.y * s.y; q.z = s.z * s.z; q.w = s.w * s.w;
            *(float4*)&st2[idx] = q;
        }
        __syncthreads();
        int wv = t >> 6, lane = t & 63;
        int oBase = blk * 32 + wv * 8;               // 16 blocks x 4 waves x 8 o
        #pragma unroll
        for (int oo = 0; oo < 8; ++oo) {
            int o = oBase + oo;
            const float4* wr = (const float4*)(w2 + (size_t)o * 512 + lane * 8);
            float4 a = wr[0], c = wr[1];
            float p[16];
            #pragma unroll
            for (int b = 0; b < 16; ++b) {
                const float4* s = (const float4*)&st2[b * 512 + lane * 8];
                float4 s0 = s[0], s1 = s[1];
                p[b] = a.x * s0.x + a.y * s0.y + a.z * s0.z + a.w * s0.w
                     + c.x * s1.x + c.y * s1.y + c.z * s1.z + c.w * s1.w;
            }
            #pragma unroll
            for (int d = 1; d < 64; d <<= 1)
                #pragma unroll
                for (int b = 0; b < 16; ++b) p[b] += __shfl_xor(p[b], d);
            if (lane < 16) invn[lane * 512 + o] = 1.0f / sqrtf(p[lane]);
        }
    } else {
        // ---- imgpad: NCHW fp32 -> padded channels-last bf16, style-premul.
        // 64-ch x 2-row tiles; 128 B contiguous store segments. (R7/R8 body.)
        __shared__ float tile[2][64][65];
        int idx = blk - 16;
        int ic = idx & 7, h0 = ((idx >> 3) & 31) * 2, b = idx >> 8;
        int t = threadIdx.x;
        int i0 = ic * 64;
        {
            int li = t >> 2;            // 0..63 channel within chunk
            int w0 = (t & 3) * 16;      // 0,16,32,48
            #pragma unroll
            for (int r = 0; r < 2; ++r) {
                const float* src = imgs + (((size_t)(b * 512 + i0 + li) * 64 + h0 + r) * 64 + w0);
                float4 v0 = ((const float4*)src)[0];
                float4 v1 = ((const float4*)src)[1];
                float4 v2 = ((const float4*)src)[2];
                float4 v3 = ((const float4*)src)[3];
                tile[r][li][w0 +  0] = v0.x; tile[r][li][w0 +  1] = v0.y;
                tile[r][li][w0 +  2] = v0.z; tile[r][li][w0 +  3] = v0.w;
                tile[r][li][w0 +  4] = v1.x; tile[r][li][w0 +  5] = v1.y;
                tile[r][li][w0 +  6] = v1.z; tile[r][li][w0 +  7] = v1.w;
                tile[r][li][w0 +  8] = v2.x; tile[r][li][w0 +  9] = v2.y;
                tile[r][li][w0 + 10] = v2.z; tile[r][li][w0 + 11] = v2.w;
                tile[r][li][w0 + 12] = v3.x; tile[r][li][w0 + 13] = v3.y;
                tile[r][li][w0 + 14] = v3.z; tile[r][li][w0 + 15] = v3.w;
            }
        }
        __syncthreads();
        {
            int c0 = (t & 7) * 8;       // 0..56: 8 lanes x 16 B = 128 B segments
            float st[8];
            #pragma unroll
            for (int j = 0; j < 8; ++j) st[j] = style[b * 512 + i0 + c0 + j];
            #pragma unroll
            for (int r = 0; r < 2; ++r) {
                #pragma unroll
                for (int g = 0; g < 2; ++g) {
                    int w = (t >> 3) + g * 32;   // 0..63
                    bf16x8 v;
                    #pragma unroll
                    for (int j = 0; j < 8; ++j) v[j] = (__bf16)(tile[r][c0 + j][w] * st[j]);
                    __bf16* dst = imgpad + (((size_t)b * PY + (h0 + r + 1)) * PX + (w + 1)) * 512 + i0 + c0;
                    *(bf16x8*)dst = v;
                }
            }
        }
    }
}

// ---------------------------------------------------------------- main conv
//
// EXACT Round-3/8 structure (best measured: conv 265 us, MfmaUtil 53.5,
// SQ_LDS_BANK_CONFLICT == 0). R4 (A-hoist), R5 (1-barrier/triple-buf) and
// R7 (32x32x16 shape) all regressed — do not modify without A/B data.
//
// 256x256 tile, BK=64, 8 waves (2M x 4N), 128 KiB LDS, 2 barriers per K-tile:
//   ph0: read 8 bf + 4 af ; stage A-half0(t+1) ; M0
//   ph1: read 4 af        ; stage A-half1(t+1) ; M1
//   BAR          <- Bs[p] write guard
//   ph2: read 4 af        ; stage B-half0(t+2) ; M2
//   ph3: read 4 af        ; stage B-half1(t+2) ; M3
//   vmcnt(4) ; BAR
//
// Hazard ledger:
//  - Bs[p] writes (B(t+2), ph2/3) vs Bs[p] reads (bf, ph0): every wave's bf
//    reads retire before its M0/M1; all waves past M1 at mid-BAR; stages
//    issue after it. OK.
//  - As[p^1] writes (A(t+1), ph0/1) vs t-1's af reads: retired before t-1's
//    M3 -> before t-1's end-BAR. OK.
//  - vmcnt(4) at tile end: outstanding = B(t+1),A(t+1),B(t+2) (issue order);
//    drains B(t+1)+A(t+1), leaves B(t+2) in flight. Tails drain to 0.
// LDS swizzle: linear LDS dest; global SOURCE k-slot permuted per lane
// (slot = (l&7)^(l>>3)); frag reads use slot = kslot ^ (row&7).

#define BM 256
#define BN 256
#define BK 64
#define NT 72   // K tiles: 9 taps * (512/64)

#define BAR() { __builtin_amdgcn_sched_barrier(0);                            \
                __builtin_amdgcn_s_barrier();                                 \
                __builtin_amdgcn_sched_barrier(0); }

// frag reads: PTR carries lane base (+wave row block, +r16*128, +slot for its ks)
#define RA(PTR, BUFL, MI) (*(const bf16x8*)((PTR) + (BUFL) * 32768 + (MI) * 2048))
#define RB(PTR, BUFL, NI) (*(const bf16x8*)((PTR) + (BUFL) * 32768 + (NI) * 2048))

// staging LDS dests (wave-uniform)
#define DSTA(BUFL, H, J) (&As[BUFL][(((H) * 128 + (J) * 64) + (wv << 3)) * 64])
#define DSTB(BUFL, H, J) (&Bs[BUFL][(((H) * 128 + (J) * 64) + (wv << 3)) * 64])

#define MFMA_PH(Q)                                                            \
    __builtin_amdgcn_s_setprio(1);                                            \
    _Pragma("unroll") for (int e = 0; e < 2; ++e) {                           \
      _Pragma("unroll") for (int ni = 0; ni < 4; ++ni) {                      \
        acc[2*(Q)+e][ni] = __builtin_amdgcn_mfma_f32_16x16x32_bf16(           \
            af[e][0], bf[ni][0], acc[2*(Q)+e][ni], 0, 0, 0);                  \
        acc[2*(Q)+e][ni] = __builtin_amdgcn_mfma_f32_16x16x32_bf16(           \
            af[e][1], bf[ni][1], acc[2*(Q)+e][ni], 0, 0, 0);                  \
      }                                                                       \
    }                                                                         \
    __builtin_amdgcn_s_setprio(0);

#define TILE(BUF, T, DO_A, DO_B, VME) {                                       \
    /* ph0: all B-frags + A mi0,1; stage A-half0(T+1) */                      \
    _Pragma("unroll") for (int ni = 0; ni < 4; ++ni) {                        \
        bf[ni][0] = RB(ldsB0, BUF, ni); bf[ni][1] = RB(ldsB1, BUF, ni);       \
    }                                                                         \
    af[0][0] = RA(ldsA0, BUF, 0); af[0][1] = RA(ldsA1, BUF, 0);               \
    af[1][0] = RA(ldsA0, BUF, 1); af[1][1] = RA(ldsA1, BUF, 1);               \
    if (DO_A) { int ka = ((T) + 1) * 64;                                      \
        load_lds16(aG00 + ka, DSTA((BUF) ^ 1, 0, 0));                         \
        load_lds16(aG01 + ka, DSTA((BUF) ^ 1, 0, 1)); }                       \
    MFMA_PH(0)                                                                \
    /* ph1: A mi2,3; stage A-half1(T+1) */                                    \
    af[0][0] = RA(ldsA0, BUF, 2); af[0][1] = RA(ldsA1, BUF, 2);               \
    af[1][0] = RA(ldsA0, BUF, 3); af[1][1] = RA(ldsA1, BUF, 3);               \
    if (DO_A) { int ka = ((T) + 1) * 64;                                      \
        load_lds16(aG10 + ka, DSTA((BUF) ^ 1, 1, 0));                         \
        load_lds16(aG11 + ka, DSTA((BUF) ^ 1, 1, 1)); }                       \
    MFMA_PH(1)                                                                \
    BAR();   /* B-region guard */                                             \
    /* ph2: A mi4,5; stage B-half0(T+2) */                                    \
    af[0][0] = RA(ldsA0, BUF, 4); af[0][1] = RA(ldsA1, BUF, 4);               \
    af[1][0] = RA(ldsA0, BUF, 5); af[1][1] = RA(ldsA1, BUF, 5);               \
    int bd2_##BUF = 0; (void)bd2_##BUF;                                       \
    if (DO_B) { int t2 = (T) + 2; int tap2 = t2 >> 3; int ic2 = t2 & 7;       \
        int dy2 = tap2 / 3, dx2 = tap2 - 3 * dy2;                             \
        bd2_##BUF = (dy2 * PX + dx2) * 512 + ic2 * 64;                        \
        load_lds16(bG00 + bd2_##BUF, DSTB(BUF, 0, 0));                        \
        load_lds16(bG01 + bd2_##BUF, DSTB(BUF, 0, 1)); }                      \
    MFMA_PH(2)                                                                \
    /* ph3: A mi6,7; stage B-half1(T+2); counted vmcnt */                     \
    af[0][0] = RA(ldsA0, BUF, 6); af[0][1] = RA(ldsA1, BUF, 6);               \
    af[1][0] = RA(ldsA0, BUF, 7); af[1][1] = RA(ldsA1, BUF, 7);               \
    if (DO_B) {                                                               \
        load_lds16(bG10 + bd2_##BUF, DSTB(BUF, 1, 0));                        \
        load_lds16(bG11 + bd2_##BUF, DSTB(BUF, 1, 1)); }                      \
    MFMA_PH(3)                                                                \
    asm volatile("s_waitcnt vmcnt(" #VME ")" ::: "memory");                   \
    __builtin_amdgcn_sched_barrier(0);                                        \
    BAR();                                                                    \
}

// out[b,o,p] = leaky( invn[b,o] * (wsh[o,:] . ximg[b,p,:]) + conv_b[o] + noise*nw )
__global__ __launch_bounds__(512, 2) void conv_kernel(
    const __bf16* __restrict__ wsh,
    const __bf16* __restrict__ imgpad,
    const float*  __restrict__ invn,
    const float*  __restrict__ conv_b,
    const float*  __restrict__ noise,
    const float*  __restrict__ nw_p,
    float* __restrict__ out)
{
    __shared__ __attribute__((aligned(16))) __bf16 As[2][BM * BK];  // 64 KiB
    __shared__ __attribute__((aligned(16))) __bf16 Bs[2][BN * BK];  // 64 KiB

    const int tid = threadIdx.x;
    const int nt = blockIdx.x, mt = blockIdx.y, b = blockIdx.z;
    const int n0 = nt * BN, m0 = mt * BM;

    const int lane = tid & 63;
    const int wv = tid >> 6;          // 0..7
    const int wmi = wv & 1;           // M wave index (2)
    const int wni = wv >> 1;          // N wave index (4)

    const __bf16* iB = imgpad + (size_t)b * PY * PX * CI;

    // ---- staging per-thread constants
    const int r0   = (wv << 3) + (lane >> 3);        // 0..63: row within 64-row quarter
    const int ks_g = (lane & 7) ^ (lane >> 3);       // pre-swizzled global k-slot

    // A sources (h,j): row = m0 + h*128 + j*64 + r0, k = tile*64 + ks_g*8
    const __bf16* aG00 = wsh + (size_t)(m0 +   0 +  0 + r0) * KTOT + ks_g * 8;
    const __bf16* aG01 = wsh + (size_t)(m0 +   0 + 64 + r0) * KTOT + ks_g * 8;
    const __bf16* aG10 = wsh + (size_t)(m0 + 128 +  0 + r0) * KTOT + ks_g * 8;
    const __bf16* aG11 = wsh + (size_t)(m0 + 128 + 64 + r0) * KTOT + ks_g * 8;

    // B sources (h,j): pixel p = n0 + h*128 + j*64 + r0 -> y = nt*4+2h+j, x = r0
    const __bf16* bG00 = iB + ((size_t)(nt * 4 + 0) * PX + r0) * 512 + ks_g * 8;
    const __bf16* bG01 = iB + ((size_t)(nt * 4 + 1) * PX + r0) * 512 + ks_g * 8;
    const __bf16* bG10 = iB + ((size_t)(nt * 4 + 2) * PX + r0) * 512 + ks_g * 8;
    const __bf16* bG11 = iB + ((size_t)(nt * 4 + 3) * PX + r0) * 512 + ks_g * 8;

    // ---- fragment-read per-lane bases (byte math; slot = kslot ^ (row&7))
    const int r16 = lane & 15, q4 = lane >> 4, r7 = lane & 7;
    const int s0 = (q4 ^ r7) << 4;                   // ks=0 slot bytes
    const char* ldsA0 = (const char*)&As[0][0] + wmi * 16384 + r16 * 128 + s0;
    const char* ldsA1 = (const char*)&As[0][0] + wmi * 16384 + r16 * 128 + (s0 ^ 64);
    const char* ldsB0 = (const char*)&Bs[0][0] + wni * 8192  + r16 * 128 + s0;
    const char* ldsB1 = (const char*)&Bs[0][0] + wni * 8192  + r16 * 128 + (s0 ^ 64);

    floatx4 acc[8][4];
    #pragma unroll
    for (int mi = 0; mi < 8; ++mi)
        #pragma unroll
        for (int ni = 0; ni < 4; ++ni)
            acc[mi][ni] = (floatx4)(0.f);

    // ---- prologue: A(0), B(0), B(1); leave B(1) in flight
    load_lds16(aG00, DSTA(0, 0, 0));
    load_lds16(aG01, DSTA(0, 0, 1));
    load_lds16(aG10, DSTA(0, 1, 0));
    load_lds16(aG11, DSTA(0, 1, 1));
    load_lds16(bG00, DSTB(0, 0, 0));          // bd(0) = 0 (tap0, ic0)
    load_lds16(bG01, DSTB(0, 0, 1));
    load_lds16(bG10, DSTB(0, 1, 0));
    load_lds16(bG11, DSTB(0, 1, 1));
    load_lds16(bG00 + 64, DSTB(1, 0, 0));     // bd(1) = 64 (tap0, ic1)
    load_lds16(bG01 + 64, DSTB(1, 0, 1));
    load_lds16(bG10 + 64, DSTB(1, 1, 0));
    load_lds16(bG11 + 64, DSTB(1, 1, 1));
    asm volatile("s_waitcnt vmcnt(4)" ::: "memory");
    __builtin_amdgcn_sched_barrier(0);
    BAR();

    bf16x8 af[2][2];
    bf16x8 bf[4][2];

    #pragma unroll 1
    for (int it = 0; it < 35; ++it) {
        int t0 = it * 2;
        TILE(0, t0,     true, true, 4)
        TILE(1, t0 + 1, true, true, 4)
    }
    // tiles 70, 71: no B prefetch left; tile 70 stages A(71) then drains fully
    TILE(0, 70, true,  false, 0)
    TILE(1, 71, false, false, 0)

    // ---- epilogue: * invn[b,o] + conv_b + noise*nw, LeakyReLU(0.2)
    float nwv = nw_p[0];
    #pragma unroll
    for (int ni = 0; ni < 4; ++ni) {
        int col = n0 + wni * 64 + ni * 16 + r16;         // pixel
        float nz = noise[b * NPIX + col] * nwv;
        #pragma unroll
        for (int mi = 0; mi < 8; ++mi) {
            int rowo = m0 + wmi * 128 + mi * 16 + q4 * 4; // output channel base
            #pragma unroll
            for (int rr = 0; rr < 4; ++rr) {
                float sc = invn[b * 512 + rowo + rr];
                float vv = acc[mi][ni][rr] * sc + conv_b[rowo + rr] + nz;
                out[(((size_t)b * CO + rowo + rr) << 12) + col] = vv >= 0.f ? vv : LEAK * vv;
            }
        }
    }
}

// ---------------------------------------------------------------- launch

extern "C" void kernel_launch(void* const* d_in, const int* in_sizes, int n_in,
                              void* d_out, int out_size, void* d_ws, size_t ws_size,
                              hipStream_t stream) {
    const float* imgs    = (const float*)d_in[0];
    const float* w_embs  = (const float*)d_in[1];
    const float* noise   = (const float*)d_in[2];
    const float* conv_w  = (const float*)d_in[3];
    const float* conv_b  = (const float*)d_in[4];
    const float* style_w = (const float*)d_in[5];
    const float* style_b = (const float*)d_in[6];
    const float* nw      = (const float*)d_in[7];
    float* out = (float*)d_out;

    char* ws = (char*)d_ws;
    size_t off = 0;
    __bf16* wsh = (__bf16*)(ws + off);       off += (size_t)CO * KTOT * 2;           // 4.7 MB
    __bf16* imgpad = (__bf16*)(ws + off);    off += IMGPAD_ELEMS * 2;                // 71.4 MB
    float* style = (float*)(ws + off);       off += (size_t)B_ * CI * 4;
    float* invn  = (float*)(ws + off);       off += (size_t)B_ * CO * 4;
    float* w2    = (float*)(ws + off);       off += (size_t)CO * CI * 4;

    // 3 launches total: prep1 (style | wsh+w2 | halo), prep2 (invn | imgpad),
    // conv. Tests the launch-overhead hypothesis for the invariant ~259 us
    // non-conv time (R8: 5 launches, same kernel bodies).
    prep1_kernel<<<dim3(192), 256, 0, stream>>>(w_embs, style_w, style_b,
                                                conv_w, style, wsh, w2, imgpad);
    prep2_kernel<<<dim3(16 + 4096), 256, 0, stream>>>(w2, style, imgs, invn, imgpad);
    conv_kernel<<<dim3(NPIX / BN, CO / BM, B_), 512, 0, stream>>>(
        wsh, imgpad, invn, conv_b, noise, nw, out);
}